// Round 12
// baseline (412.743 us; speedup 1.0000x reference)
//
#include <hip/hip_runtime.h>
#include <stdint.h>

#define N_TOK 8192
#define HDIM  1024
#define NEXP  8
#define CAP   16384   // per-expert rowid list capacity
#define MAXTILE 136   // >= sum_e ceil(ce/128) = 128 + 7 max

typedef __bf16 bf16x8 __attribute__((ext_vector_type(8)));
typedef float  f32x4  __attribute__((ext_vector_type(4)));

__device__ inline unsigned short f2bf(float f) {
  union { float f; unsigned u; } v; v.f = f;
  return (unsigned short)((v.u + 0x7fffu + ((v.u >> 16) & 1u)) >> 16);  // RNE
}

__device__ inline float bf2f(unsigned short b) {
  union { unsigned u; float f; } v; v.u = (unsigned)b << 16; return v.f;
}

// tanh-form gelu (max |err| vs exact erf-gelu ~1e-3, far under 2.7e-2 threshold)
__device__ inline float gelu_f(float x) {
  float y = 0.7978845608028654f * (x + 0.044715f * x * x * x);
  y = fminf(fmaxf(y, -15.f), 15.f);
  float t = __expf(2.f * y);
  return 0.5f * x * (1.f + (t - 1.f) / (t + 1.f));
}

__device__ inline void gld_lds16(const void* gptr, void* lptr) {
  __builtin_amdgcn_global_load_lds(
      (const __attribute__((address_space(1))) void*)(uintptr_t)gptr,
      (__attribute__((address_space(3))) void*)(uintptr_t)lptr,
      16, 0, 0);
}

// ---------------- f32 -> bf16 conversion (weights) ----------------
__global__ __launch_bounds__(256) void cvt_kernel(const float* __restrict__ src,
                                                  unsigned short* __restrict__ dst,
                                                  int n4) {
  int i = blockIdx.x * 256 + threadIdx.x;
  int stride = gridDim.x * 256;
  for (; i < n4; i += stride) {
    float4 v = reinterpret_cast<const float4*>(src)[i];
    ushort4 o;
    o.x = f2bf(v.x); o.y = f2bf(v.y); o.z = f2bf(v.z); o.w = f2bf(v.w);
    reinterpret_cast<ushort4*>(dst)[i] = o;
  }
}

// ---------------- router: logits, top-2, softmax -> pair/probs (NO atomics) ----------------
__global__ __launch_bounds__(256) void router_kernel(
    const float* __restrict__ tokens, const float* __restrict__ rw,
    unsigned short* __restrict__ tokb, int* __restrict__ pair,
    float* __restrict__ probs) {
  int wid = threadIdx.x >> 6, lane = threadIdx.x & 63;
  int n = blockIdx.x * 4 + wid;
  const float4* trow = (const float4*)(tokens + (size_t)n * HDIM);
  ushort4* tdst = (ushort4*)(tokb + (size_t)n * HDIM);
  float acc[NEXP];
#pragma unroll
  for (int e = 0; e < NEXP; e++) acc[e] = 0.f;
#pragma unroll
  for (int it = 0; it < 4; it++) {
    int c4 = it * 64 + lane;
    float4 tv = trow[c4];
    ushort4 o;
    o.x = f2bf(tv.x); o.y = f2bf(tv.y); o.z = f2bf(tv.z); o.w = f2bf(tv.w);
    tdst[c4] = o;
#pragma unroll
    for (int e = 0; e < NEXP; e++) {
      float4 w = ((const float4*)(rw + e * HDIM))[c4];
      acc[e] += tv.x * w.x + tv.y * w.y + tv.z * w.z + tv.w * w.w;
    }
  }
#pragma unroll
  for (int e = 0; e < NEXP; e++) {
#pragma unroll
    for (int off = 32; off > 0; off >>= 1) acc[e] += __shfl_xor(acc[e], off, 64);
  }
  if (lane == 0) {
    int e0 = 0; float s0 = acc[0];
#pragma unroll
    for (int e = 1; e < NEXP; e++) if (acc[e] > s0) { s0 = acc[e]; e0 = e; }
    int e1 = -1; float s1 = -3.4e38f;
#pragma unroll
    for (int e = 0; e < NEXP; e++) if (e != e0 && acc[e] > s1) { s1 = acc[e]; e1 = e; }
    float z  = expf(s1 - s0);
    float p0 = 1.f / (1.f + z);
    pair[n] = e0 | (e1 << 8);
    probs[2 * n]     = p0;
    probs[2 * n + 1] = z * p0;
  }
}

// ---------------- dispatch: deterministic per-expert compaction via LDS scan ----------------
__global__ __launch_bounds__(1024) void dispatch_kernel(
    const int* __restrict__ pair, int* __restrict__ counts,
    int* __restrict__ rowids) {
  int e = blockIdx.x;
  int t = threadIdx.x;
  __shared__ int sc[1024];
  int p8[8];
  int c = 0;
#pragma unroll
  for (int i = 0; i < 8; i++) {
    p8[i] = pair[t * 8 + i];
    c += ((p8[i] & 255) == e) + (((p8[i] >> 8) & 255) == e);
  }
  sc[t] = c;
  __syncthreads();
  for (int off = 1; off < 1024; off <<= 1) {
    int v = (t >= off) ? sc[t - off] : 0;
    __syncthreads();
    sc[t] += v;
    __syncthreads();
  }
  if (t == 1023) counts[e] = sc[1023];
  int* dst = rowids + e * CAP + (sc[t] - c);
#pragma unroll
  for (int i = 0; i < 8; i++) {
    int n = t * 8 + i;
    if ((p8[i] & 255) == e)        *dst++ = 2 * n;
    if (((p8[i] >> 8) & 255) == e) *dst++ = 2 * n + 1;
  }
}

// ---------------- worklist: compact (expert, rb) tile descriptors (128-row units) --------
__global__ void worklist_kernel(const int* __restrict__ counts, int* __restrict__ wl) {
  if (threadIdx.x == 0) {
    int p = 0;
    for (int e = 0; e < NEXP; e++) {
      int nt = (counts[e] + 127) >> 7;
      for (int i = 0; i < nt; i++) { wl[1 + p] = (e << 16) | i; p++; }
    }
    wl[0] = p;
  }
}

// ---- gemm0 (fc1+gelu): 128 rows x 256 cols (2 col-halves from ONE staged A), BK=64 ----
// 256 thr / 4 waves; per step: stage 48 KB, 512 MFMA = 128 MFMA/wave (2x R9's drain cover).
// cb=blockIdx&7 -> 256-col slice per XCD = 4 MiB = exact L2 fit. 1088 blocks (half of R9).
__global__ __launch_bounds__(256) void moe_gemm0(
    const unsigned short* __restrict__ tokb,
    const unsigned short* __restrict__ w1b,
    const float* __restrict__ b1,
    const int* __restrict__ counts, const int* __restrict__ rowids,
    const int* __restrict__ wl,
    unsigned short* __restrict__ Hbuf) {
  constexpr int KT = 16;                   // K=1024 / 64

  int cb   = blockIdx.x & 7;               // 256-col slice, one per XCD
  int tile = blockIdx.x >> 3;
  if (tile >= wl[0]) return;
  int d  = wl[1 + tile];
  int e  = d >> 16;
  int rb = d & 0xffff;                     // 128-row units
  int ce = counts[e];
  const int* rl = rowids + e * CAP + rb * 128;

  int t = threadIdx.x;
  __shared__ __align__(16) char smem[49152];   // A[128][64] @0 (16 KB), B[256][64] @16384 (32 KB)

  // staging: chunk c = i*256+t -> LDS byte c*16 (linear); row=c>>3, phys col-chunk=c&7
  // read swizzle j_phys = j ^ (row&7) => source logical chunk jsrc = (t&7)^((t>>3)&7)
  int jsrc = (t & 7) ^ ((t >> 3) & 7);
  const char* asrc[4];
  const char* bsrc[8];
#pragma unroll
  for (int i = 0; i < 4; i++) {
    int rr = i * 32 + (t >> 3);
    int rid = (rb * 128 + rr < ce) ? rl[rr] : rl[0];   // clamp tail to valid row
    asrc[i] = (const char*)(tokb + (long)(rid >> 1) * HDIM) + jsrc * 16;
  }
#pragma unroll
  for (int i = 0; i < 8; i++) {
    int rr = i * 32 + (t >> 3);                        // B rows 0..255 = cols cb*256..+255
    bsrc[i] = (const char*)(w1b + ((long)e * 2048 + cb * 256 + rr) * HDIM) + jsrc * 16;
  }

  f32x4 acc[2][4][4];
#pragma unroll
  for (int h = 0; h < 2; h++)
#pragma unroll
    for (int mi = 0; mi < 4; mi++)
#pragma unroll
      for (int ni = 0; ni < 4; ni++) {
        f32x4 z = {0.f, 0.f, 0.f, 0.f};
        acc[h][mi][ni] = z;
      }

  int lane = t & 63, wid = t >> 6;
  int wr = wid >> 1, wc = wid & 1;   // 2x2 waves; per wave 64 rows x 64 cols per half
  int lr = lane >> 4, lc = lane & 15;

  for (int kt = 0; kt < KT; kt++) {
#pragma unroll
    for (int i = 0; i < 4; i++)
      gld_lds16(asrc[i] + kt * 128, smem + i * 4096 + t * 16);
#pragma unroll
    for (int i = 0; i < 8; i++)
      gld_lds16(bsrc[i] + kt * 128, smem + 16384 + i * 4096 + t * 16);
    __syncthreads();
#pragma unroll
    for (int ks = 0; ks < 2; ks++) {
      int j = ks * 4 + lr;
      bf16x8 af[4];
#pragma unroll
      for (int mi = 0; mi < 4; mi++) {
        int rr = wr * 64 + mi * 16 + lc;
        af[mi] = *(const bf16x8*)(smem + rr * 128 + ((j ^ (rr & 7)) << 4));
      }
#pragma unroll
      for (int h = 0; h < 2; h++) {
        bf16x8 bfv[4];
#pragma unroll
        for (int ni = 0; ni < 4; ni++) {
          int rr = h * 128 + wc * 64 + ni * 16 + lc;
          bfv[ni] = *(const bf16x8*)(smem + 16384 + rr * 128 + ((j ^ (rr & 7)) << 4));
        }
        __builtin_amdgcn_s_setprio(1);
#pragma unroll
        for (int mi = 0; mi < 4; mi++)
#pragma unroll
          for (int ni = 0; ni < 4; ni++)
            acc[h][mi][ni] = __builtin_amdgcn_mfma_f32_16x16x32_bf16(af[mi], bfv[ni], acc[h][mi][ni], 0, 0, 0);
        __builtin_amdgcn_s_setprio(0);
      }
    }
    __syncthreads();
  }

  // ---- epilogue: two 128-col halves through smem (32 KB each), chunk-swizzled ----
  float bcol[2][4];
#pragma unroll
  for (int h = 0; h < 2; h++)
#pragma unroll
    for (int ni = 0; ni < 4; ni++)
      bcol[h][ni] = b1[e * 2048 + cb * 256 + h * 128 + wc * 64 + ni * 16 + lc];

#pragma unroll
  for (int h = 0; h < 2; h++) {
#pragma unroll
    for (int mi = 0; mi < 4; mi++) {
#pragma unroll
      for (int r4 = 0; r4 < 4; r4++) {
        int lrow = wr * 64 + mi * 16 + lr * 4 + r4;     // 0..127
#pragma unroll
        for (int ni = 0; ni < 4; ni++) {
          int colh = wc * 64 + ni * 16 + lc;            // 0..127 within half
          float x = gelu_f(acc[h][mi][ni][r4] + bcol[h][ni]);
          int j = colh >> 3;
          *(unsigned short*)(smem + lrow * 256 + ((j ^ (lrow & 15)) << 4) + (colh & 7) * 2) = f2bf(x);
        }
      }
    }
    __syncthreads();
    int row = t >> 1, hh = t & 1;   // 2 threads/row, 128 B each
    if (rb * 128 + row < ce) {
      int rid = rl[row];
      char* dst = (char*)(Hbuf + (long)rid * 2048 + cb * 256 + h * 128) + hh * 128;
#pragma unroll
      for (int i = 0; i < 8; i++) {
        int jj = hh * 8 + i;
        *(int4*)(dst + i * 16) = *(const int4*)(smem + row * 256 + ((jj ^ (row & 15)) << 4));
      }
    }
    __syncthreads();
  }
}

// ---- gemm1 (fc2+prob): R9-verbatim winning config — 128x128, CB=8, cb=XCD, BK=128 ----
__global__ __launch_bounds__(256) void moe_gemm1(
    const unsigned short* __restrict__ Hbuf,
    const unsigned short* __restrict__ w2b,
    const float* __restrict__ b2,
    const int* __restrict__ counts, const int* __restrict__ rowids,
    const int* __restrict__ wl, const float* __restrict__ probs,
    unsigned short* __restrict__ Ybuf) {
  constexpr int KT = 16;                   // K=2048 / 128

  int cb   = blockIdx.x & 7;               // XCD pin: B-slice 4 MiB = L2 fit
  int tile = blockIdx.x >> 3;
  if (tile >= wl[0]) return;
  int d  = wl[1 + tile];
  int e  = d >> 16;
  int rb = d & 0xffff;
  int ce = counts[e];
  const int* rl = rowids + e * CAP + rb * 128;

  int t = threadIdx.x;
  __shared__ __align__(16) char smem[65536];  // A[128][128]bf16 @0, B @32768

  int jsrc = (t & 15) ^ ((t >> 4) & 15);
  const char* asrc[8];
  const char* bsrc[8];
#pragma unroll
  for (int i = 0; i < 8; i++) {
    int rr = i * 16 + (t >> 4);
    int rid = (rb * 128 + rr < ce) ? rl[rr] : rl[0];
    asrc[i] = (const char*)(Hbuf + (long)rid * 2048) + jsrc * 16;
    bsrc[i] = (const char*)(w2b + ((long)e * 1024 + cb * 128 + rr) * 2048) + jsrc * 16;
  }

  f32x4 acc[4][4];
#pragma unroll
  for (int mi = 0; mi < 4; mi++)
#pragma unroll
    for (int ni = 0; ni < 4; ni++) {
      f32x4 z = {0.f, 0.f, 0.f, 0.f};
      acc[mi][ni] = z;
    }

  int lane = t & 63, wid = t >> 6;
  int wr = wid >> 1, wc = wid & 1;        // 2x2 wave grid, 64x64 per wave
  int lr = lane >> 4, lc = lane & 15;

  for (int kt = 0; kt < KT; kt++) {
#pragma unroll
    for (int i = 0; i < 8; i++)
      gld_lds16(asrc[i] + kt * 256, smem + i * 4096 + t * 16);
#pragma unroll
    for (int i = 0; i < 8; i++)
      gld_lds16(bsrc[i] + kt * 256, smem + 32768 + i * 4096 + t * 16);
    __syncthreads();
#pragma unroll
    for (int ks = 0; ks < 4; ks++) {
      bf16x8 af[4], bfr[4];
      int j = ks * 4 + lr;
#pragma unroll
      for (int mi = 0; mi < 4; mi++) {
        int rr = wr * 64 + mi * 16 + lc;
        af[mi] = *(const bf16x8*)(smem + rr * 256 + ((j ^ (rr & 15)) << 4));
      }
#pragma unroll
      for (int ni = 0; ni < 4; ni++) {
        int rr = wc * 64 + ni * 16 + lc;
        bfr[ni] = *(const bf16x8*)(smem + 32768 + rr * 256 + ((j ^ (rr & 15)) << 4));
      }
      __builtin_amdgcn_s_setprio(1);
#pragma unroll
      for (int mi = 0; mi < 4; mi++)
#pragma unroll
        for (int ni = 0; ni < 4; ni++)
          acc[mi][ni] = __builtin_amdgcn_mfma_f32_16x16x32_bf16(af[mi], bfr[ni], acc[mi][ni], 0, 0, 0);
      __builtin_amdgcn_s_setprio(0);
    }
    __syncthreads();
  }

  float bcol[4];
#pragma unroll
  for (int ni = 0; ni < 4; ni++)
    bcol[ni] = b2[e * 1024 + cb * 128 + wc * 64 + ni * 16 + lc];

#pragma unroll
  for (int mi = 0; mi < 4; mi++) {
#pragma unroll
    for (int r4 = 0; r4 < 4; r4++) {
      int lrow = wr * 64 + mi * 16 + lr * 4 + r4;
      float p = (rb * 128 + lrow < ce) ? probs[rl[lrow]] : 0.f;
#pragma unroll
      for (int ni = 0; ni < 4; ni++) {
        int col = wc * 64 + ni * 16 + lc;
        float x = (acc[mi][ni][r4] + bcol[ni]) * p;
        int j = col >> 3;
        *(unsigned short*)(smem + lrow * 256 + ((j ^ (lrow & 15)) << 4) + (col & 7) * 2) = f2bf(x);
      }
    }
  }
  __syncthreads();

  int row = t >> 1, h = t & 1;
  if (rb * 128 + row < ce) {
    int rid = rl[row];
    char* dst = (char*)(Ybuf + (long)rid * 1024 + cb * 128) + h * 128;
#pragma unroll
    for (int i = 0; i < 8; i++) {
      int j = h * 8 + i;
      *(int4*)(dst + i * 16) = *(const int4*)(smem + row * 256 + ((j ^ (row & 15)) << 4));
    }
  }
}

// ---------------- merge: out[n] = Y[2n] + Y[2n+1]  (bf16 -> f32) ----------------
typedef short short8v __attribute__((ext_vector_type(8)));
__global__ __launch_bounds__(256) void merge_kernel(const unsigned short* __restrict__ Y,
                                                    float* __restrict__ out) {
  int i = blockIdx.x * 256 + threadIdx.x;   // 1M chunks of 8 elems
  int n = i >> 7, c = (i & 127) * 8;
  const short8v a = *(const short8v*)(Y + (long)(2 * n) * HDIM + c);
  const short8v b = *(const short8v*)(Y + (long)(2 * n + 1) * HDIM + c);
  float4 o0, o1;
#pragma unroll
  for (int k = 0; k < 8; k++) {
    float v = bf2f((unsigned short)a[k]) + bf2f((unsigned short)b[k]);
    if (k < 4) (&o0.x)[k] = v; else (&o1.x)[k - 4] = v;
  }
  float4* dst = (float4*)(out + (long)n * HDIM + c);
  dst[0] = o0; dst[1] = o1;
}

extern "C" void kernel_launch(void* const* d_in, const int* in_sizes, int n_in,
                              void* d_out, int out_size, void* d_ws, size_t ws_size,
                              hipStream_t stream) {
  const float* tokens   = (const float*)d_in[0];
  const float* router_w = (const float*)d_in[1];
  const float* w1       = (const float*)d_in[2];
  const float* b1       = (const float*)d_in[3];
  const float* w2       = (const float*)d_in[4];
  const float* b2       = (const float*)d_in[5];
  float* out = (float*)d_out;

  // ws layout (bytes):
  //   0        counts[8]
  //   64       rowids[8][16384] int          (512 KiB)
  //   +512K    probs[16384] f32              (64 KiB)
  //   +64K     pair[8192] int                (32 KiB)
  //   +32K     wl[1+136] int                 (~1 KiB)
  //   1 MiB    tokens_bf16 [8192][1024]      (16 MiB)
  //   +16M     w1b [8][2048][1024] bf16      (32 MiB)  <- becomes Ybuf after gemm0
  //   +48M     w2b [8][1024][2048] bf16      (32 MiB)
  //   +80M     Hbuf [16384][2048] bf16       (64 MiB)   total ~145 MiB
  char* ws = (char*)d_ws;
  int*            counts = (int*)ws;
  int*            rowids = (int*)(ws + 64);
  float*          probs  = (float*)(ws + 64 + NEXP * CAP * 4);
  int*            pair   = (int*)(ws + 64 + NEXP * CAP * 4 + N_TOK * 2 * 4);
  int*            wl     = (int*)(ws + 64 + NEXP * CAP * 4 + N_TOK * 2 * 4 + N_TOK * 4);
  unsigned short* tokb   = (unsigned short*)(ws + (1u << 20));
  unsigned short* w1b    = (unsigned short*)(ws + (1u << 20) + 16777216u);
  unsigned short* w2b    = (unsigned short*)(ws + (1u << 20) + 16777216u + 33554432u);
  unsigned short* Hbuf   = (unsigned short*)(ws + (1u << 20) + 16777216u + 67108864u);
  unsigned short* Ybuf   = w1b;  // w1 weights dead after gemm0; 32 MiB = 16384x1024 bf16

  cvt_kernel<<<2048, 256, 0, stream>>>(w1, w1b, NEXP * 2048 * 1024 / 4);
  cvt_kernel<<<2048, 256, 0, stream>>>(w2, w2b, NEXP * 1024 * 2048 / 4);
  router_kernel<<<N_TOK / 4, 256, 0, stream>>>(tokens, router_w, tokb, pair, probs);
  dispatch_kernel<<<NEXP, 1024, 0, stream>>>(pair, counts, rowids);
  worklist_kernel<<<1, 64, 0, stream>>>(counts, wl);
  moe_gemm0<<<MAXTILE * 8, 256, 0, stream>>>(tokb, w1b, b1, counts, rowids, wl, Hbuf);
  moe_gemm1<<<MAXTILE * 8, 256, 0, stream>>>(Hbuf, w2b, b2, counts, rowids, wl, probs, Ybuf);
  merge_kernel<<<N_TOK * HDIM / 8 / 256, 256, 0, stream>>>(Ybuf, out);
}

// Round 13
// 349.953 us; speedup vs baseline: 1.1794x; 1.1794x over previous
//
#include <hip/hip_runtime.h>
#include <stdint.h>

#define N_TOK 8192
#define HDIM  1024
#define NEXP  8
#define CAP   16384   // per-expert rowid list capacity
#define MAXTILE 136   // >= sum_e ceil(ce/128) = 128 + 7 max

typedef __bf16 bf16x8 __attribute__((ext_vector_type(8)));
typedef float  f32x4  __attribute__((ext_vector_type(4)));

__device__ inline unsigned short f2bf(float f) {
  union { float f; unsigned u; } v; v.f = f;
  return (unsigned short)((v.u + 0x7fffu + ((v.u >> 16) & 1u)) >> 16);  // RNE
}

__device__ inline float bf2f(unsigned short b) {
  union { unsigned u; float f; } v; v.u = (unsigned)b << 16; return v.f;
}

// tanh-form gelu (max |err| vs exact erf-gelu ~1e-3, far under 2.7e-2 threshold)
__device__ inline float gelu_f(float x) {
  float y = 0.7978845608028654f * (x + 0.044715f * x * x * x);
  y = fminf(fmaxf(y, -15.f), 15.f);
  float t = __expf(2.f * y);
  return 0.5f * x * (1.f + (t - 1.f) / (t + 1.f));
}

__device__ inline void gld_lds16(const void* gptr, void* lptr) {
  __builtin_amdgcn_global_load_lds(
      (const __attribute__((address_space(1))) void*)(uintptr_t)gptr,
      (__attribute__((address_space(3))) void*)(uintptr_t)lptr,
      16, 0, 0);
}

// ---------------- f32 -> bf16 conversion (weights) ----------------
__global__ __launch_bounds__(256) void cvt_kernel(const float* __restrict__ src,
                                                  unsigned short* __restrict__ dst,
                                                  int n4) {
  int i = blockIdx.x * 256 + threadIdx.x;
  int stride = gridDim.x * 256;
  for (; i < n4; i += stride) {
    float4 v = reinterpret_cast<const float4*>(src)[i];
    ushort4 o;
    o.x = f2bf(v.x); o.y = f2bf(v.y); o.z = f2bf(v.z); o.w = f2bf(v.w);
    reinterpret_cast<ushort4*>(dst)[i] = o;
  }
}

// ---------------- router: logits, top-2, softmax -> pair/probs (NO atomics) ----------------
__global__ __launch_bounds__(256) void router_kernel(
    const float* __restrict__ tokens, const float* __restrict__ rw,
    unsigned short* __restrict__ tokb, int* __restrict__ pair,
    float* __restrict__ probs) {
  int wid = threadIdx.x >> 6, lane = threadIdx.x & 63;
  int n = blockIdx.x * 4 + wid;
  const float4* trow = (const float4*)(tokens + (size_t)n * HDIM);
  ushort4* tdst = (ushort4*)(tokb + (size_t)n * HDIM);
  float acc[NEXP];
#pragma unroll
  for (int e = 0; e < NEXP; e++) acc[e] = 0.f;
#pragma unroll
  for (int it = 0; it < 4; it++) {
    int c4 = it * 64 + lane;
    float4 tv = trow[c4];
    ushort4 o;
    o.x = f2bf(tv.x); o.y = f2bf(tv.y); o.z = f2bf(tv.z); o.w = f2bf(tv.w);
    tdst[c4] = o;
#pragma unroll
    for (int e = 0; e < NEXP; e++) {
      float4 w = ((const float4*)(rw + e * HDIM))[c4];
      acc[e] += tv.x * w.x + tv.y * w.y + tv.z * w.z + tv.w * w.w;
    }
  }
#pragma unroll
  for (int e = 0; e < NEXP; e++) {
#pragma unroll
    for (int off = 32; off > 0; off >>= 1) acc[e] += __shfl_xor(acc[e], off, 64);
  }
  if (lane == 0) {
    int e0 = 0; float s0 = acc[0];
#pragma unroll
    for (int e = 1; e < NEXP; e++) if (acc[e] > s0) { s0 = acc[e]; e0 = e; }
    int e1 = -1; float s1 = -3.4e38f;
#pragma unroll
    for (int e = 0; e < NEXP; e++) if (e != e0 && acc[e] > s1) { s1 = acc[e]; e1 = e; }
    float z  = expf(s1 - s0);
    float p0 = 1.f / (1.f + z);
    pair[n] = e0 | (e1 << 8);
    probs[2 * n]     = p0;
    probs[2 * n + 1] = z * p0;
  }
}

// ---------------- dispatch: deterministic per-expert compaction via LDS scan ----------------
__global__ __launch_bounds__(1024) void dispatch_kernel(
    const int* __restrict__ pair, int* __restrict__ counts,
    int* __restrict__ rowids) {
  int e = blockIdx.x;
  int t = threadIdx.x;
  __shared__ int sc[1024];
  int p8[8];
  int c = 0;
#pragma unroll
  for (int i = 0; i < 8; i++) {
    p8[i] = pair[t * 8 + i];
    c += ((p8[i] & 255) == e) + (((p8[i] >> 8) & 255) == e);
  }
  sc[t] = c;
  __syncthreads();
  for (int off = 1; off < 1024; off <<= 1) {
    int v = (t >= off) ? sc[t - off] : 0;
    __syncthreads();
    sc[t] += v;
    __syncthreads();
  }
  if (t == 1023) counts[e] = sc[1023];
  int* dst = rowids + e * CAP + (sc[t] - c);
#pragma unroll
  for (int i = 0; i < 8; i++) {
    int n = t * 8 + i;
    if ((p8[i] & 255) == e)        *dst++ = 2 * n;
    if (((p8[i] >> 8) & 255) == e) *dst++ = 2 * n + 1;
  }
}

// ---------------- worklist: compact (expert, rb) tile descriptors (128-row units) --------
__global__ void worklist_kernel(const int* __restrict__ counts, int* __restrict__ wl) {
  if (threadIdx.x == 0) {
    int p = 0;
    for (int e = 0; e < NEXP; e++) {
      int nt = (counts[e] + 127) >> 7;
      for (int i = 0; i < nt; i++) { wl[1 + p] = (e << 16) | i; p++; }
    }
    wl[0] = p;
  }
}

// ---- gemm0 (fc1+gelu), run as TWO structural clones of gemm1 over w1's col halves ----
// Each dispatch: 128x128 tile, CB=8, cb=blockIdx&7 (XCD pin), BK=128, KT=8, grid 1088 —
// bit-identical block geometry to moe_gemm1. hofs in {0,1024} selects the w1/Hbuf col half.
__global__ __launch_bounds__(256) void moe_gemm0(
    const unsigned short* __restrict__ tokb,
    const unsigned short* __restrict__ w1b,
    const float* __restrict__ b1,
    const int* __restrict__ counts, const int* __restrict__ rowids,
    const int* __restrict__ wl,
    unsigned short* __restrict__ Hbuf, int hofs) {
  constexpr int KT = 8;                    // K=1024 / 128

  int cb   = blockIdx.x & 7;               // XCD pin: per-XCD B slice = 2 MiB (L2 fit)
  int tile = blockIdx.x >> 3;
  if (tile >= wl[0]) return;
  int d  = wl[1 + tile];
  int e  = d >> 16;
  int rb = d & 0xffff;
  int ce = counts[e];
  const int* rl = rowids + e * CAP + rb * 128;

  int t = threadIdx.x;
  __shared__ __align__(16) char smem[65536];  // A[128][128]bf16 @0, B @32768

  int jsrc = (t & 15) ^ ((t >> 4) & 15);
  const char* asrc[8];
  const char* bsrc[8];
#pragma unroll
  for (int i = 0; i < 8; i++) {
    int rr = i * 16 + (t >> 4);
    int rid = (rb * 128 + rr < ce) ? rl[rr] : rl[0];
    asrc[i] = (const char*)(tokb + (long)(rid >> 1) * HDIM) + jsrc * 16;
    bsrc[i] = (const char*)(w1b + ((long)e * 2048 + hofs + cb * 128 + rr) * HDIM) + jsrc * 16;
  }

  f32x4 acc[4][4];
#pragma unroll
  for (int mi = 0; mi < 4; mi++)
#pragma unroll
    for (int ni = 0; ni < 4; ni++) {
      f32x4 z = {0.f, 0.f, 0.f, 0.f};
      acc[mi][ni] = z;
    }

  int lane = t & 63, wid = t >> 6;
  int wr = wid >> 1, wc = wid & 1;        // 2x2 wave grid, 64x64 per wave
  int lr = lane >> 4, lc = lane & 15;

  for (int kt = 0; kt < KT; kt++) {
#pragma unroll
    for (int i = 0; i < 8; i++)
      gld_lds16(asrc[i] + kt * 256, smem + i * 4096 + t * 16);
#pragma unroll
    for (int i = 0; i < 8; i++)
      gld_lds16(bsrc[i] + kt * 256, smem + 32768 + i * 4096 + t * 16);
    __syncthreads();
#pragma unroll
    for (int ks = 0; ks < 4; ks++) {
      bf16x8 af[4], bfr[4];
      int j = ks * 4 + lr;
#pragma unroll
      for (int mi = 0; mi < 4; mi++) {
        int rr = wr * 64 + mi * 16 + lc;
        af[mi] = *(const bf16x8*)(smem + rr * 256 + ((j ^ (rr & 15)) << 4));
      }
#pragma unroll
      for (int ni = 0; ni < 4; ni++) {
        int rr = wc * 64 + ni * 16 + lc;
        bfr[ni] = *(const bf16x8*)(smem + 32768 + rr * 256 + ((j ^ (rr & 15)) << 4));
      }
      __builtin_amdgcn_s_setprio(1);
#pragma unroll
      for (int mi = 0; mi < 4; mi++)
#pragma unroll
        for (int ni = 0; ni < 4; ni++)
          acc[mi][ni] = __builtin_amdgcn_mfma_f32_16x16x32_bf16(af[mi], bfr[ni], acc[mi][ni], 0, 0, 0);
      __builtin_amdgcn_s_setprio(0);
    }
    __syncthreads();
  }

  // ---- epilogue (gemm1-structure + gelu): swizzled smem staging, 16B stores ----
  float bcol[4];
#pragma unroll
  for (int ni = 0; ni < 4; ni++)
    bcol[ni] = b1[e * 2048 + hofs + cb * 128 + wc * 64 + ni * 16 + lc];

#pragma unroll
  for (int mi = 0; mi < 4; mi++) {
#pragma unroll
    for (int r4 = 0; r4 < 4; r4++) {
      int lrow = wr * 64 + mi * 16 + lr * 4 + r4;
#pragma unroll
      for (int ni = 0; ni < 4; ni++) {
        int col = wc * 64 + ni * 16 + lc;
        float x = gelu_f(acc[mi][ni][r4] + bcol[ni]);
        int j = col >> 3;
        *(unsigned short*)(smem + lrow * 256 + ((j ^ (lrow & 15)) << 4) + (col & 7) * 2) = f2bf(x);
      }
    }
  }
  __syncthreads();

  int row = t >> 1, h = t & 1;
  if (rb * 128 + row < ce) {
    int rid = rl[row];
    char* dst = (char*)(Hbuf + (long)rid * 2048 + hofs + cb * 128) + h * 128;
#pragma unroll
    for (int i = 0; i < 8; i++) {
      int j = h * 8 + i;
      *(int4*)(dst + i * 16) = *(const int4*)(smem + row * 256 + ((j ^ (row & 15)) << 4));
    }
  }
}

// ---- gemm1 (fc2+prob): R9-verbatim winning config — 128x128, CB=8, cb=XCD, BK=128 ----
__global__ __launch_bounds__(256) void moe_gemm1(
    const unsigned short* __restrict__ Hbuf,
    const unsigned short* __restrict__ w2b,
    const float* __restrict__ b2,
    const int* __restrict__ counts, const int* __restrict__ rowids,
    const int* __restrict__ wl, const float* __restrict__ probs,
    unsigned short* __restrict__ Ybuf) {
  constexpr int KT = 16;                   // K=2048 / 128

  int cb   = blockIdx.x & 7;               // XCD pin: B-slice 4 MiB = L2 fit
  int tile = blockIdx.x >> 3;
  if (tile >= wl[0]) return;
  int d  = wl[1 + tile];
  int e  = d >> 16;
  int rb = d & 0xffff;
  int ce = counts[e];
  const int* rl = rowids + e * CAP + rb * 128;

  int t = threadIdx.x;
  __shared__ __align__(16) char smem[65536];  // A[128][128]bf16 @0, B @32768

  int jsrc = (t & 15) ^ ((t >> 4) & 15);
  const char* asrc[8];
  const char* bsrc[8];
#pragma unroll
  for (int i = 0; i < 8; i++) {
    int rr = i * 16 + (t >> 4);
    int rid = (rb * 128 + rr < ce) ? rl[rr] : rl[0];
    asrc[i] = (const char*)(Hbuf + (long)rid * 2048) + jsrc * 16;
    bsrc[i] = (const char*)(w2b + ((long)e * 1024 + cb * 128 + rr) * 2048) + jsrc * 16;
  }

  f32x4 acc[4][4];
#pragma unroll
  for (int mi = 0; mi < 4; mi++)
#pragma unroll
    for (int ni = 0; ni < 4; ni++) {
      f32x4 z = {0.f, 0.f, 0.f, 0.f};
      acc[mi][ni] = z;
    }

  int lane = t & 63, wid = t >> 6;
  int wr = wid >> 1, wc = wid & 1;        // 2x2 wave grid, 64x64 per wave
  int lr = lane >> 4, lc = lane & 15;

  for (int kt = 0; kt < KT; kt++) {
#pragma unroll
    for (int i = 0; i < 8; i++)
      gld_lds16(asrc[i] + kt * 256, smem + i * 4096 + t * 16);
#pragma unroll
    for (int i = 0; i < 8; i++)
      gld_lds16(bsrc[i] + kt * 256, smem + 32768 + i * 4096 + t * 16);
    __syncthreads();
#pragma unroll
    for (int ks = 0; ks < 4; ks++) {
      bf16x8 af[4], bfr[4];
      int j = ks * 4 + lr;
#pragma unroll
      for (int mi = 0; mi < 4; mi++) {
        int rr = wr * 64 + mi * 16 + lc;
        af[mi] = *(const bf16x8*)(smem + rr * 256 + ((j ^ (rr & 15)) << 4));
      }
#pragma unroll
      for (int ni = 0; ni < 4; ni++) {
        int rr = wc * 64 + ni * 16 + lc;
        bfr[ni] = *(const bf16x8*)(smem + 32768 + rr * 256 + ((j ^ (rr & 15)) << 4));
      }
      __builtin_amdgcn_s_setprio(1);
#pragma unroll
      for (int mi = 0; mi < 4; mi++)
#pragma unroll
        for (int ni = 0; ni < 4; ni++)
          acc[mi][ni] = __builtin_amdgcn_mfma_f32_16x16x32_bf16(af[mi], bfr[ni], acc[mi][ni], 0, 0, 0);
      __builtin_amdgcn_s_setprio(0);
    }
    __syncthreads();
  }

  float bcol[4];
#pragma unroll
  for (int ni = 0; ni < 4; ni++)
    bcol[ni] = b2[e * 1024 + cb * 128 + wc * 64 + ni * 16 + lc];

#pragma unroll
  for (int mi = 0; mi < 4; mi++) {
#pragma unroll
    for (int r4 = 0; r4 < 4; r4++) {
      int lrow = wr * 64 + mi * 16 + lr * 4 + r4;
      float p = (rb * 128 + lrow < ce) ? probs[rl[lrow]] : 0.f;
#pragma unroll
      for (int ni = 0; ni < 4; ni++) {
        int col = wc * 64 + ni * 16 + lc;
        float x = (acc[mi][ni][r4] + bcol[ni]) * p;
        int j = col >> 3;
        *(unsigned short*)(smem + lrow * 256 + ((j ^ (lrow & 15)) << 4) + (col & 7) * 2) = f2bf(x);
      }
    }
  }
  __syncthreads();

  int row = t >> 1, h = t & 1;
  if (rb * 128 + row < ce) {
    int rid = rl[row];
    char* dst = (char*)(Ybuf + (long)rid * 1024 + cb * 128) + h * 128;
#pragma unroll
    for (int i = 0; i < 8; i++) {
      int j = h * 8 + i;
      *(int4*)(dst + i * 16) = *(const int4*)(smem + row * 256 + ((j ^ (row & 15)) << 4));
    }
  }
}

// ---------------- merge: out[n] = Y[2n] + Y[2n+1]  (bf16 -> f32) ----------------
typedef short short8v __attribute__((ext_vector_type(8)));
__global__ __launch_bounds__(256) void merge_kernel(const unsigned short* __restrict__ Y,
                                                    float* __restrict__ out) {
  int i = blockIdx.x * 256 + threadIdx.x;   // 1M chunks of 8 elems
  int n = i >> 7, c = (i & 127) * 8;
  const short8v a = *(const short8v*)(Y + (long)(2 * n) * HDIM + c);
  const short8v b = *(const short8v*)(Y + (long)(2 * n + 1) * HDIM + c);
  float4 o0, o1;
#pragma unroll
  for (int k = 0; k < 8; k++) {
    float v = bf2f((unsigned short)a[k]) + bf2f((unsigned short)b[k]);
    if (k < 4) (&o0.x)[k] = v; else (&o1.x)[k - 4] = v;
  }
  float4* dst = (float4*)(out + (long)n * HDIM + c);
  dst[0] = o0; dst[1] = o1;
}

extern "C" void kernel_launch(void* const* d_in, const int* in_sizes, int n_in,
                              void* d_out, int out_size, void* d_ws, size_t ws_size,
                              hipStream_t stream) {
  const float* tokens   = (const float*)d_in[0];
  const float* router_w = (const float*)d_in[1];
  const float* w1       = (const float*)d_in[2];
  const float* b1       = (const float*)d_in[3];
  const float* w2       = (const float*)d_in[4];
  const float* b2       = (const float*)d_in[5];
  float* out = (float*)d_out;

  // ws layout (bytes):
  //   0        counts[8]
  //   64       rowids[8][16384] int          (512 KiB)
  //   +512K    probs[16384] f32              (64 KiB)
  //   +64K     pair[8192] int                (32 KiB)
  //   +32K     wl[1+136] int                 (~1 KiB)
  //   1 MiB    tokens_bf16 [8192][1024]      (16 MiB)
  //   +16M     w1b [8][2048][1024] bf16      (32 MiB)  <- becomes Ybuf after gemm0
  //   +48M     w2b [8][1024][2048] bf16      (32 MiB)
  //   +80M     Hbuf [16384][2048] bf16       (64 MiB)   total ~145 MiB
  char* ws = (char*)d_ws;
  int*            counts = (int*)ws;
  int*            rowids = (int*)(ws + 64);
  float*          probs  = (float*)(ws + 64 + NEXP * CAP * 4);
  int*            pair   = (int*)(ws + 64 + NEXP * CAP * 4 + N_TOK * 2 * 4);
  int*            wl     = (int*)(ws + 64 + NEXP * CAP * 4 + N_TOK * 2 * 4 + N_TOK * 4);
  unsigned short* tokb   = (unsigned short*)(ws + (1u << 20));
  unsigned short* w1b    = (unsigned short*)(ws + (1u << 20) + 16777216u);
  unsigned short* w2b    = (unsigned short*)(ws + (1u << 20) + 16777216u + 33554432u);
  unsigned short* Hbuf   = (unsigned short*)(ws + (1u << 20) + 16777216u + 67108864u);
  unsigned short* Ybuf   = w1b;  // w1 weights dead after gemm0; 32 MiB = 16384x1024 bf16

  cvt_kernel<<<2048, 256, 0, stream>>>(w1, w1b, NEXP * 2048 * 1024 / 4);
  cvt_kernel<<<2048, 256, 0, stream>>>(w2, w2b, NEXP * 1024 * 2048 / 4);
  router_kernel<<<N_TOK / 4, 256, 0, stream>>>(tokens, router_w, tokb, pair, probs);
  dispatch_kernel<<<NEXP, 1024, 0, stream>>>(pair, counts, rowids);
  worklist_kernel<<<1, 64, 0, stream>>>(counts, wl);
  // fc1 as two gemm1-clones over w1 column halves (disjoint Hbuf columns)
  moe_gemm0<<<MAXTILE * 8, 256, 0, stream>>>(tokb, w1b, b1, counts, rowids, wl, Hbuf, 0);
  moe_gemm0<<<MAXTILE * 8, 256, 0, stream>>>(tokb, w1b, b1, counts, rowids, wl, Hbuf, 1024);
  moe_gemm1<<<MAXTILE * 8, 256, 0, stream>>>(Hbuf, w2b, b2, counts, rowids, wl, probs, Ybuf);
  merge_kernel<<<N_TOK * HDIM / 8 / 256, 256, 0, stream>>>(Ybuf, out);
}

// Round 14
// 328.693 us; speedup vs baseline: 1.2557x; 1.0647x over previous
//
#include <hip/hip_runtime.h>
#include <stdint.h>

#define N_TOK 8192
#define HDIM  1024
#define NEXP  8
#define CAP   16384   // per-expert rowid list capacity
#define MAXTILE 136   // >= sum_e ceil(ce/128) = 128 + 7 max

typedef __bf16 bf16x8 __attribute__((ext_vector_type(8)));
typedef float  f32x4  __attribute__((ext_vector_type(4)));

__device__ inline unsigned short f2bf(float f) {
  union { float f; unsigned u; } v; v.f = f;
  return (unsigned short)((v.u + 0x7fffu + ((v.u >> 16) & 1u)) >> 16);  // RNE
}

__device__ inline float bf2f(unsigned short b) {
  union { unsigned u; float f; } v; v.u = (unsigned)b << 16; return v.f;
}

// tanh-form gelu (max |err| vs exact erf-gelu ~1e-3, far under 2.7e-2 threshold)
__device__ inline float gelu_f(float x) {
  float y = 0.7978845608028654f * (x + 0.044715f * x * x * x);
  y = fminf(fmaxf(y, -15.f), 15.f);
  float t = __expf(2.f * y);
  return 0.5f * x * (1.f + (t - 1.f) / (t + 1.f));
}

__device__ inline void gld_lds16(const void* gptr, void* lptr) {
  __builtin_amdgcn_global_load_lds(
      (const __attribute__((address_space(1))) void*)(uintptr_t)gptr,
      (__attribute__((address_space(3))) void*)(uintptr_t)lptr,
      16, 0, 0);
}

// ---------------- f32 -> bf16 conversion (weights) ----------------
__global__ __launch_bounds__(256) void cvt_kernel(const float* __restrict__ src,
                                                  unsigned short* __restrict__ dst,
                                                  int n4) {
  int i = blockIdx.x * 256 + threadIdx.x;
  int stride = gridDim.x * 256;
  for (; i < n4; i += stride) {
    float4 v = reinterpret_cast<const float4*>(src)[i];
    ushort4 o;
    o.x = f2bf(v.x); o.y = f2bf(v.y); o.z = f2bf(v.z); o.w = f2bf(v.w);
    reinterpret_cast<ushort4*>(dst)[i] = o;
  }
}

// ---------------- router: logits, top-2, softmax -> pair/probs (NO atomics) ----------------
__global__ __launch_bounds__(256) void router_kernel(
    const float* __restrict__ tokens, const float* __restrict__ rw,
    unsigned short* __restrict__ tokb, int* __restrict__ pair,
    float* __restrict__ probs) {
  int wid = threadIdx.x >> 6, lane = threadIdx.x & 63;
  int n = blockIdx.x * 4 + wid;
  const float4* trow = (const float4*)(tokens + (size_t)n * HDIM);
  ushort4* tdst = (ushort4*)(tokb + (size_t)n * HDIM);
  float acc[NEXP];
#pragma unroll
  for (int e = 0; e < NEXP; e++) acc[e] = 0.f;
#pragma unroll
  for (int it = 0; it < 4; it++) {
    int c4 = it * 64 + lane;
    float4 tv = trow[c4];
    ushort4 o;
    o.x = f2bf(tv.x); o.y = f2bf(tv.y); o.z = f2bf(tv.z); o.w = f2bf(tv.w);
    tdst[c4] = o;
#pragma unroll
    for (int e = 0; e < NEXP; e++) {
      float4 w = ((const float4*)(rw + e * HDIM))[c4];
      acc[e] += tv.x * w.x + tv.y * w.y + tv.z * w.z + tv.w * w.w;
    }
  }
#pragma unroll
  for (int e = 0; e < NEXP; e++) {
#pragma unroll
    for (int off = 32; off > 0; off >>= 1) acc[e] += __shfl_xor(acc[e], off, 64);
  }
  if (lane == 0) {
    int e0 = 0; float s0 = acc[0];
#pragma unroll
    for (int e = 1; e < NEXP; e++) if (acc[e] > s0) { s0 = acc[e]; e0 = e; }
    int e1 = -1; float s1 = -3.4e38f;
#pragma unroll
    for (int e = 0; e < NEXP; e++) if (e != e0 && acc[e] > s1) { s1 = acc[e]; e1 = e; }
    float z  = expf(s1 - s0);
    float p0 = 1.f / (1.f + z);
    pair[n] = e0 | (e1 << 8);
    probs[2 * n]     = p0;
    probs[2 * n + 1] = z * p0;
  }
}

// ---------------- dispatch: deterministic per-expert compaction via LDS scan ----------------
__global__ __launch_bounds__(1024) void dispatch_kernel(
    const int* __restrict__ pair, int* __restrict__ counts,
    int* __restrict__ rowids) {
  int e = blockIdx.x;
  int t = threadIdx.x;
  __shared__ int sc[1024];
  int p8[8];
  int c = 0;
#pragma unroll
  for (int i = 0; i < 8; i++) {
    p8[i] = pair[t * 8 + i];
    c += ((p8[i] & 255) == e) + (((p8[i] >> 8) & 255) == e);
  }
  sc[t] = c;
  __syncthreads();
  for (int off = 1; off < 1024; off <<= 1) {
    int v = (t >= off) ? sc[t - off] : 0;
    __syncthreads();
    sc[t] += v;
    __syncthreads();
  }
  if (t == 1023) counts[e] = sc[1023];
  int* dst = rowids + e * CAP + (sc[t] - c);
#pragma unroll
  for (int i = 0; i < 8; i++) {
    int n = t * 8 + i;
    if ((p8[i] & 255) == e)        *dst++ = 2 * n;
    if (((p8[i] >> 8) & 255) == e) *dst++ = 2 * n + 1;
  }
}

// ---------------- worklist: compact (expert, rb) tile descriptors (128-row units) --------
__global__ void worklist_kernel(const int* __restrict__ counts, int* __restrict__ wl) {
  if (threadIdx.x == 0) {
    int p = 0;
    for (int e = 0; e < NEXP; e++) {
      int nt = (counts[e] + 127) >> 7;
      for (int i = 0; i < nt; i++) { wl[1 + p] = (e << 16) | i; p++; }
    }
    wl[0] = p;
  }
}

// ---- gemm0 (fc1+gelu): single dispatch, HALF-MAJOR ordering. 128x128 tile, BK=128, KT=8 ---
// bid < 1088: w1 cols 0..1023 (cb = bid&7, one 128-col slice per XCD -> per-XCD B = 2 MiB,
// L2 slack vs R9's 4 MiB exact-fit). bid >= 1088: cols 1024..2047. Tile-major within half
// preserves A-panel sharing across the 8 XCD-siblings.
__global__ __launch_bounds__(256) void moe_gemm0(
    const unsigned short* __restrict__ tokb,
    const unsigned short* __restrict__ w1b,
    const float* __restrict__ b1,
    const int* __restrict__ counts, const int* __restrict__ rowids,
    const int* __restrict__ wl,
    unsigned short* __restrict__ Hbuf) {
  constexpr int KT = 8;                    // K=1024 / 128

  int bid  = blockIdx.x;
  int half = (bid >= MAXTILE * 8) ? 1 : 0;
  int rem  = bid - half * (MAXTILE * 8);
  int cb   = rem & 7;                      // XCD pin: per-XCD B slice = 2 MiB this phase
  int tile = rem >> 3;
  int hofs = half << 10;                   // 0 or 1024
  if (tile >= wl[0]) return;
  int d  = wl[1 + tile];
  int e  = d >> 16;
  int rb = d & 0xffff;
  int ce = counts[e];
  const int* rl = rowids + e * CAP + rb * 128;

  int t = threadIdx.x;
  __shared__ __align__(16) char smem[65536];  // A[128][128]bf16 @0, B @32768

  int jsrc = (t & 15) ^ ((t >> 4) & 15);
  const char* asrc[8];
  const char* bsrc[8];
#pragma unroll
  for (int i = 0; i < 8; i++) {
    int rr = i * 16 + (t >> 4);
    int rid = (rb * 128 + rr < ce) ? rl[rr] : rl[0];
    asrc[i] = (const char*)(tokb + (long)(rid >> 1) * HDIM) + jsrc * 16;
    bsrc[i] = (const char*)(w1b + ((long)e * 2048 + hofs + cb * 128 + rr) * HDIM) + jsrc * 16;
  }

  f32x4 acc[4][4];
#pragma unroll
  for (int mi = 0; mi < 4; mi++)
#pragma unroll
    for (int ni = 0; ni < 4; ni++) {
      f32x4 z = {0.f, 0.f, 0.f, 0.f};
      acc[mi][ni] = z;
    }

  int lane = t & 63, wid = t >> 6;
  int wr = wid >> 1, wc = wid & 1;        // 2x2 wave grid, 64x64 per wave
  int lr = lane >> 4, lc = lane & 15;

  for (int kt = 0; kt < KT; kt++) {
#pragma unroll
    for (int i = 0; i < 8; i++)
      gld_lds16(asrc[i] + kt * 256, smem + i * 4096 + t * 16);
#pragma unroll
    for (int i = 0; i < 8; i++)
      gld_lds16(bsrc[i] + kt * 256, smem + 32768 + i * 4096 + t * 16);
    __syncthreads();
#pragma unroll
    for (int ks = 0; ks < 4; ks++) {
      bf16x8 af[4], bfr[4];
      int j = ks * 4 + lr;
#pragma unroll
      for (int mi = 0; mi < 4; mi++) {
        int rr = wr * 64 + mi * 16 + lc;
        af[mi] = *(const bf16x8*)(smem + rr * 256 + ((j ^ (rr & 15)) << 4));
      }
#pragma unroll
      for (int ni = 0; ni < 4; ni++) {
        int rr = wc * 64 + ni * 16 + lc;
        bfr[ni] = *(const bf16x8*)(smem + 32768 + rr * 256 + ((j ^ (rr & 15)) << 4));
      }
      __builtin_amdgcn_s_setprio(1);
#pragma unroll
      for (int mi = 0; mi < 4; mi++)
#pragma unroll
        for (int ni = 0; ni < 4; ni++)
          acc[mi][ni] = __builtin_amdgcn_mfma_f32_16x16x32_bf16(af[mi], bfr[ni], acc[mi][ni], 0, 0, 0);
      __builtin_amdgcn_s_setprio(0);
    }
    __syncthreads();
  }

  // ---- epilogue: swizzled smem staging + gelu, 16B stores ----
  float bcol[4];
#pragma unroll
  for (int ni = 0; ni < 4; ni++)
    bcol[ni] = b1[e * 2048 + hofs + cb * 128 + wc * 64 + ni * 16 + lc];

#pragma unroll
  for (int mi = 0; mi < 4; mi++) {
#pragma unroll
    for (int r4 = 0; r4 < 4; r4++) {
      int lrow = wr * 64 + mi * 16 + lr * 4 + r4;
#pragma unroll
      for (int ni = 0; ni < 4; ni++) {
        int col = wc * 64 + ni * 16 + lc;
        float x = gelu_f(acc[mi][ni][r4] + bcol[ni]);
        int j = col >> 3;
        *(unsigned short*)(smem + lrow * 256 + ((j ^ (lrow & 15)) << 4) + (col & 7) * 2) = f2bf(x);
      }
    }
  }
  __syncthreads();

  int row = t >> 1, h = t & 1;
  if (rb * 128 + row < ce) {
    int rid = rl[row];
    char* dst = (char*)(Hbuf + (long)rid * 2048 + hofs + cb * 128) + h * 128;
#pragma unroll
    for (int i = 0; i < 8; i++) {
      int j = h * 8 + i;
      *(int4*)(dst + i * 16) = *(const int4*)(smem + row * 256 + ((j ^ (row & 15)) << 4));
    }
  }
}

// ---- gemm1 (fc2+prob): R9-verbatim winning config — 128x128, CB=8, cb=XCD, BK=128 ----
__global__ __launch_bounds__(256) void moe_gemm1(
    const unsigned short* __restrict__ Hbuf,
    const unsigned short* __restrict__ w2b,
    const float* __restrict__ b2,
    const int* __restrict__ counts, const int* __restrict__ rowids,
    const int* __restrict__ wl, const float* __restrict__ probs,
    unsigned short* __restrict__ Ybuf) {
  constexpr int KT = 16;                   // K=2048 / 128

  int cb   = blockIdx.x & 7;               // XCD pin
  int tile = blockIdx.x >> 3;
  if (tile >= wl[0]) return;
  int d  = wl[1 + tile];
  int e  = d >> 16;
  int rb = d & 0xffff;
  int ce = counts[e];
  const int* rl = rowids + e * CAP + rb * 128;

  int t = threadIdx.x;
  __shared__ __align__(16) char smem[65536];  // A[128][128]bf16 @0, B @32768

  int jsrc = (t & 15) ^ ((t >> 4) & 15);
  const char* asrc[8];
  const char* bsrc[8];
#pragma unroll
  for (int i = 0; i < 8; i++) {
    int rr = i * 16 + (t >> 4);
    int rid = (rb * 128 + rr < ce) ? rl[rr] : rl[0];
    asrc[i] = (const char*)(Hbuf + (long)rid * 2048) + jsrc * 16;
    bsrc[i] = (const char*)(w2b + ((long)e * 1024 + cb * 128 + rr) * 2048) + jsrc * 16;
  }

  f32x4 acc[4][4];
#pragma unroll
  for (int mi = 0; mi < 4; mi++)
#pragma unroll
    for (int ni = 0; ni < 4; ni++) {
      f32x4 z = {0.f, 0.f, 0.f, 0.f};
      acc[mi][ni] = z;
    }

  int lane = t & 63, wid = t >> 6;
  int wr = wid >> 1, wc = wid & 1;        // 2x2 wave grid, 64x64 per wave
  int lr = lane >> 4, lc = lane & 15;

  for (int kt = 0; kt < KT; kt++) {
#pragma unroll
    for (int i = 0; i < 8; i++)
      gld_lds16(asrc[i] + kt * 256, smem + i * 4096 + t * 16);
#pragma unroll
    for (int i = 0; i < 8; i++)
      gld_lds16(bsrc[i] + kt * 256, smem + 32768 + i * 4096 + t * 16);
    __syncthreads();
#pragma unroll
    for (int ks = 0; ks < 4; ks++) {
      bf16x8 af[4], bfr[4];
      int j = ks * 4 + lr;
#pragma unroll
      for (int mi = 0; mi < 4; mi++) {
        int rr = wr * 64 + mi * 16 + lc;
        af[mi] = *(const bf16x8*)(smem + rr * 256 + ((j ^ (rr & 15)) << 4));
      }
#pragma unroll
      for (int ni = 0; ni < 4; ni++) {
        int rr = wc * 64 + ni * 16 + lc;
        bfr[ni] = *(const bf16x8*)(smem + 32768 + rr * 256 + ((j ^ (rr & 15)) << 4));
      }
      __builtin_amdgcn_s_setprio(1);
#pragma unroll
      for (int mi = 0; mi < 4; mi++)
#pragma unroll
        for (int ni = 0; ni < 4; ni++)
          acc[mi][ni] = __builtin_amdgcn_mfma_f32_16x16x32_bf16(af[mi], bfr[ni], acc[mi][ni], 0, 0, 0);
      __builtin_amdgcn_s_setprio(0);
    }
    __syncthreads();
  }

  float bcol[4];
#pragma unroll
  for (int ni = 0; ni < 4; ni++)
    bcol[ni] = b2[e * 1024 + cb * 128 + wc * 64 + ni * 16 + lc];

#pragma unroll
  for (int mi = 0; mi < 4; mi++) {
#pragma unroll
    for (int r4 = 0; r4 < 4; r4++) {
      int lrow = wr * 64 + mi * 16 + lr * 4 + r4;
      float p = (rb * 128 + lrow < ce) ? probs[rl[lrow]] : 0.f;
#pragma unroll
      for (int ni = 0; ni < 4; ni++) {
        int col = wc * 64 + ni * 16 + lc;
        float x = (acc[mi][ni][r4] + bcol[ni]) * p;
        int j = col >> 3;
        *(unsigned short*)(smem + lrow * 256 + ((j ^ (lrow & 15)) << 4) + (col & 7) * 2) = f2bf(x);
      }
    }
  }
  __syncthreads();

  int row = t >> 1, h = t & 1;
  if (rb * 128 + row < ce) {
    int rid = rl[row];
    char* dst = (char*)(Ybuf + (long)rid * 1024 + cb * 128) + h * 128;
#pragma unroll
    for (int i = 0; i < 8; i++) {
      int j = h * 8 + i;
      *(int4*)(dst + i * 16) = *(const int4*)(smem + row * 256 + ((j ^ (row & 15)) << 4));
    }
  }
}

// ---------------- merge: out[n] = Y[2n] + Y[2n+1]  (bf16 -> f32) ----------------
typedef short short8v __attribute__((ext_vector_type(8)));
__global__ __launch_bounds__(256) void merge_kernel(const unsigned short* __restrict__ Y,
                                                    float* __restrict__ out) {
  int i = blockIdx.x * 256 + threadIdx.x;   // 1M chunks of 8 elems
  int n = i >> 7, c = (i & 127) * 8;
  const short8v a = *(const short8v*)(Y + (long)(2 * n) * HDIM + c);
  const short8v b = *(const short8v*)(Y + (long)(2 * n + 1) * HDIM + c);
  float4 o0, o1;
#pragma unroll
  for (int k = 0; k < 8; k++) {
    float v = bf2f((unsigned short)a[k]) + bf2f((unsigned short)b[k]);
    if (k < 4) (&o0.x)[k] = v; else (&o1.x)[k - 4] = v;
  }
  float4* dst = (float4*)(out + (long)n * HDIM + c);
  dst[0] = o0; dst[1] = o1;
}

extern "C" void kernel_launch(void* const* d_in, const int* in_sizes, int n_in,
                              void* d_out, int out_size, void* d_ws, size_t ws_size,
                              hipStream_t stream) {
  const float* tokens   = (const float*)d_in[0];
  const float* router_w = (const float*)d_in[1];
  const float* w1       = (const float*)d_in[2];
  const float* b1       = (const float*)d_in[3];
  const float* w2       = (const float*)d_in[4];
  const float* b2       = (const float*)d_in[5];
  float* out = (float*)d_out;

  // ws layout (bytes):
  //   0        counts[8]
  //   64       rowids[8][16384] int          (512 KiB)
  //   +512K    probs[16384] f32              (64 KiB)
  //   +64K     pair[8192] int                (32 KiB)
  //   +32K     wl[1+136] int                 (~1 KiB)
  //   1 MiB    tokens_bf16 [8192][1024]      (16 MiB)
  //   +16M     w1b [8][2048][1024] bf16      (32 MiB)  <- becomes Ybuf after gemm0
  //   +48M     w2b [8][1024][2048] bf16      (32 MiB)
  //   +80M     Hbuf [16384][2048] bf16       (64 MiB)   total ~145 MiB
  char* ws = (char*)d_ws;
  int*            counts = (int*)ws;
  int*            rowids = (int*)(ws + 64);
  float*          probs  = (float*)(ws + 64 + NEXP * CAP * 4);
  int*            pair   = (int*)(ws + 64 + NEXP * CAP * 4 + N_TOK * 2 * 4);
  int*            wl     = (int*)(ws + 64 + NEXP * CAP * 4 + N_TOK * 2 * 4 + N_TOK * 4);
  unsigned short* tokb   = (unsigned short*)(ws + (1u << 20));
  unsigned short* w1b    = (unsigned short*)(ws + (1u << 20) + 16777216u);
  unsigned short* w2b    = (unsigned short*)(ws + (1u << 20) + 16777216u + 33554432u);
  unsigned short* Hbuf   = (unsigned short*)(ws + (1u << 20) + 16777216u + 67108864u);
  unsigned short* Ybuf   = w1b;  // w1 weights dead after gemm0; 32 MiB = 16384x1024 bf16

  cvt_kernel<<<2048, 256, 0, stream>>>(w1, w1b, NEXP * 2048 * 1024 / 4);
  cvt_kernel<<<2048, 256, 0, stream>>>(w2, w2b, NEXP * 1024 * 2048 / 4);
  router_kernel<<<N_TOK / 4, 256, 0, stream>>>(tokens, router_w, tokb, pair, probs);
  dispatch_kernel<<<NEXP, 1024, 0, stream>>>(pair, counts, rowids);
  worklist_kernel<<<1, 64, 0, stream>>>(counts, wl);
  // fc1: single dispatch, half-major ordering (per-XCD B slice = 2 MiB per phase)
  moe_gemm0<<<MAXTILE * 16, 256, 0, stream>>>(tokb, w1b, b1, counts, rowids, wl, Hbuf);
  moe_gemm1<<<MAXTILE * 8, 256, 0, stream>>>(Hbuf, w2b, b2, counts, rowids, wl, probs, Ybuf);
  merge_kernel<<<N_TOK * HDIM / 8 / 256, 256, 0, stream>>>(Ybuf, out);
}